// Round 16
// baseline (10848.640 us; speedup 1.0000x reference)
//
#include <hip/hip_runtime.h>
#include <stdint.h>
#include <math.h>

// ---------------------------------------------------------------------------
// Round 16: eliminate the wave-0 post-B2 serial section. The mu/ls matmul on
// h_{t+1} (R13: after B2(t), wave 0 only, ~600-cyc straggler) is identical to
// a matmul on hfh[buf] at step t+1 — which the kb loop already reads. So all
// waves fold am = mfma(ah, bmu, am) into the kb loop (+1 MFMA/kb, reusing
// ah), compute x_t redundantly pre-B1 (identical values, benign same-value
// LDS writes), and the step becomes matmul -> B1 -> epilogue -> B2 with NO
// serial tail. z/logw stay on wave 1 (R15 machinery, parity-buffered).
// All chains bitwise-identical to R13 -> absmax unchanged (9.765625e-4).
// Register risk: acc 64 + am 16 + arch ~87 = ~167 <= 170 (3 waves/SIMD).
// ---------------------------------------------------------------------------

#define HH     128
#define NG     512
#define NB     8192
#define NSAMP  100
#define NSTEP  20
#define TCAP   18
#define NHIST  126
#define NRET   127

using bfrag = __attribute__((ext_vector_type(8))) short;   // 8 bf16 = 4 VGPRs
using facc  = __attribute__((ext_vector_type(16))) float;  // 16 f32 acc

// LDS frag strides (shorts): per-(kb,hs) region 264 (8 pad), per-kb 528.
#define SHS 264
#define SKB 528
#define HFN 4224   // 8 kb * 528

// ----------------------------- threefry2x32 --------------------------------
__device__ __forceinline__ void tf2x32(uint32_t k0, uint32_t k1,
                                       uint32_t x0, uint32_t x1,
                                       uint32_t &y0, uint32_t &y1) {
  uint32_t ks2 = k0 ^ k1 ^ 0x1BD11BDAu;
  x0 += k0; x1 += k1;
#define RR(r) { x0 += x1; x1 = (x1 << (r)) | (x1 >> (32 - (r))); x1 ^= x0; }
  RR(13) RR(15) RR(26) RR(6)   x0 += k1;  x1 += ks2 + 1u;
  RR(17) RR(29) RR(16) RR(24)  x0 += ks2; x1 += k0  + 2u;
  RR(13) RR(15) RR(26) RR(6)   x0 += k0;  x1 += k1  + 3u;
  RR(17) RR(29) RR(16) RR(24)  x0 += k1;  x1 += ks2 + 4u;
  RR(13) RR(15) RR(26) RR(6)   x0 += ks2; x1 += k0  + 5u;
#undef RR
  y0 = x0; y1 = x1;
}

__device__ __forceinline__ float erfinv32(float x) {
  float w = -__logf(fmaxf(1.0f - x * x, 1e-37f));
  float p;
  if (w < 5.0f) {
    w = w - 2.5f;
    p = 2.81022636e-08f;
    p = fmaf(p, w, 3.43273939e-07f);
    p = fmaf(p, w, -3.5233877e-06f);
    p = fmaf(p, w, -4.39150654e-06f);
    p = fmaf(p, w, 0.00021858087f);
    p = fmaf(p, w, -0.00125372503f);
    p = fmaf(p, w, -0.00417768164f);
    p = fmaf(p, w, 0.246640727f);
    p = fmaf(p, w, 1.50140941f);
  } else {
    w = sqrtf(w) - 3.0f;
    p = -0.000200214257f;
    p = fmaf(p, w, 0.000100950558f);
    p = fmaf(p, w, 0.00134934322f);
    p = fmaf(p, w, -0.00367342844f);
    p = fmaf(p, w, 0.00573950773f);
    p = fmaf(p, w, -0.0076224613f);
    p = fmaf(p, w, 0.00943887047f);
    p = fmaf(p, w, 1.00167406f);
    p = fmaf(p, w, 2.83297682f);
  }
  return p * x;
}

__device__ __forceinline__ float normal32(uint32_t k0, uint32_t k1, uint32_t idx) {
  uint32_t y0, y1;
  tf2x32(k0, k1, 0u, idx, y0, y1);
  uint32_t bits = y0 ^ y1;
  float f = __uint_as_float((bits >> 9) | 0x3f800000u) - 1.0f;
  const float lo = __uint_as_float(0xBF7FFFFFu);
  float u = fmaxf(lo, f * 2.0f + lo);
  return 1.41421356f * erfinv32(u);
}

__device__ __forceinline__ float fast_sigmoid(float x) {
  return __builtin_amdgcn_rcpf(1.0f + __expf(-x));
}
__device__ __forceinline__ float fast_tanh(float x) {
  return 1.0f - 2.0f * __builtin_amdgcn_rcpf(1.0f + __expf(2.0f * x));
}

// RNE bf16 (one-time B pack only — bits unchanged vs prior rounds)
__device__ __forceinline__ unsigned short f2bf(float x) {
  uint32_t u = __float_as_uint(x);
  uint32_t r = u + 0x7fffu + ((u >> 16) & 1u);
  return (unsigned short)(r >> 16);
}
__device__ __forceinline__ float bf2f(unsigned short h) {
  return __uint_as_float(((uint32_t)h) << 16);
}

// truncation split: hi = top16(h); lo = top16(h - hi) (Sterbenz-exact sub)
__device__ __forceinline__ void split_trunc(float h, unsigned short &hi,
                                            unsigned short &lo) {
  uint32_t u = __float_as_uint(h);
  hi = (unsigned short)(u >> 16);
  float hv = __uint_as_float(u & 0xFFFF0000u);
  lo = (unsigned short)(__float_as_uint(h - hv) >> 16);
}

// ------------------------------- small kernels -----------------------------
__global__ void returns_kernel(const float* __restrict__ inp,
                               const float* __restrict__ pert,
                               float* __restrict__ ret) {
  int i = blockIdx.x * blockDim.x + threadIdx.x;
  if (i >= NRET * NB) return;
  int s = i / NB, b = i - s * NB;
  float p0 = inp[s * NB + b] * (1.0f + pert[s * NB + b]);
  float p1 = inp[(s + 1) * NB + b] * (1.0f + pert[(s + 1) * NB + b]);
  ret[i] = p1 - p0;
}

__global__ void keys_kernel(uint32_t* __restrict__ keys) {
  int id = blockIdx.x * blockDim.x + threadIdx.x;
  if (id >= NSAMP * NSTEP) return;
  int s = id / NSTEP, t = id - s * NSTEP;
  uint32_t sk0, sk1, k0, k1;
  tf2x32(0u, 42u, 0u, (uint32_t)s, sk0, sk1);
  tf2x32(sk0, sk1, 0u, (uint32_t)t, k0, k1);
  keys[2 * id] = k0; keys[2 * id + 1] = k1;
}

// B-fragment pack (RNE, unchanged): Bhi/Blo[((gct*8+kb)*64+lane)*8+j]
__global__ void pack_kernel(const float* __restrict__ W_hh,
                            const float* __restrict__ w_mu,
                            const float* __restrict__ w_ls,
                            unsigned short* __restrict__ Bhi,
                            unsigned short* __restrict__ Blo,
                            unsigned short* __restrict__ Bmu) {
  int idx = blockIdx.x * blockDim.x + threadIdx.x;
  if (idx < 65536) {
    int j = idx & 7, lane = (idx >> 3) & 63, kb = (idx >> 9) & 7, gct = idx >> 12;
    int k = kb * 16 + ((lane >> 5) << 3) + j;
    int g = (gct << 5) + (lane & 31);
    float w = W_hh[k * NG + g];
    unsigned short hi = f2bf(w);
    unsigned short lo = f2bf(w - bf2f(hi));
    Bhi[idx] = hi; Blo[idx] = lo;
  } else if (idx < 65536 + 4096) {
    int i2 = idx - 65536;
    int j = i2 & 7, lane = (i2 >> 3) & 63, kb = (i2 >> 9) & 7;
    int k = kb * 16 + ((lane >> 5) << 3) + j;
    int col = lane & 31;
    float v = (col == 0) ? w_mu[k] : (col == 1 ? w_ls[k] : 0.0f);
    Bmu[i2] = f2bf(v);
  }
}

// ------------------------------ history kernel -----------------------------
__launch_bounds__(256, 1)
__global__ void hist_kernel(const float* __restrict__ ret,
                            const float* __restrict__ W_ih,
                            const float* __restrict__ bias,
                            const unsigned short* __restrict__ Bhi,
                            const unsigned short* __restrict__ Blo,
                            float* __restrict__ hout,
                            float* __restrict__ cout) {
  __shared__ unsigned short hfh[2][HFN];
  __shared__ unsigned short hfl[2][HFN];

  const int tid  = threadIdx.x;
  const int lane = tid & 63;
  const int cg   = tid >> 6;
  const int hs   = lane >> 5;
  const int m    = lane & 31;
  const int col  = (cg << 5) + m;
  const int b0   = blockIdx.x << 5;

  float wih_r[4], bb_r[4];
#pragma unroll
  for (int gi = 0; gi < 4; ++gi) {
    wih_r[gi] = W_ih[(gi << 7) + col];
    bb_r[gi]  = bias[(gi << 7) + col];
  }

  const int coff = (col >> 4) * SKB + ((col >> 3) & 1) * SHS + (col & 7);
  const int aoff = hs * SHS + m * 8;

  float c_reg[16];
#pragma unroll
  for (int reg = 0; reg < 16; ++reg) {
    int row32 = (reg & 3) + ((reg >> 2) << 3) + (hs << 2);
    c_reg[reg] = 0.0f;
    hfh[0][coff + row32 * 8] = 0;
    hfl[0][coff + row32 * 8] = 0;
  }
  __syncthreads();

  int buf = 0;
#pragma unroll 1
  for (int t = 0; t < NHIST; ++t) {
    const int nbuf = buf ^ 1;
    facc acc[4];
#pragma unroll
    for (int reg = 0; reg < 16; ++reg) {
      int row32 = (reg & 3) + ((reg >> 2) << 3) + (hs << 2);
      float xv = ret[t * NB + b0 + row32];
#pragma unroll
      for (int gi = 0; gi < 4; ++gi)
        acc[gi][reg] = fmaf(xv, wih_r[gi], bb_r[gi]);
    }
#pragma unroll 1
    for (int kb = 0; kb < 8; ++kb) {
      bfrag ah = *(const bfrag*)&hfh[buf][kb * SKB + aoff];
      bfrag al = *(const bfrag*)&hfl[buf][kb * SKB + aoff];
#pragma unroll
      for (int gp = 0; gp < 2; ++gp) {
        const int g0 = 2 * gp, g1 = 2 * gp + 1;
        const int off0 = ((((g0 << 2) + cg) << 3) + kb) * 512 + lane * 8;
        const int off1 = ((((g1 << 2) + cg) << 3) + kb) * 512 + lane * 8;
        bfrag bh0 = *(const bfrag*)&Bhi[off0];
        bfrag bl0 = *(const bfrag*)&Blo[off0];
        bfrag bh1 = *(const bfrag*)&Bhi[off1];
        bfrag bl1 = *(const bfrag*)&Blo[off1];
        acc[g0] = __builtin_amdgcn_mfma_f32_32x32x16_bf16(ah, bh0, acc[g0], 0, 0, 0);
        acc[g1] = __builtin_amdgcn_mfma_f32_32x32x16_bf16(ah, bh1, acc[g1], 0, 0, 0);
        acc[g0] = __builtin_amdgcn_mfma_f32_32x32x16_bf16(al, bh0, acc[g0], 0, 0, 0);
        acc[g1] = __builtin_amdgcn_mfma_f32_32x32x16_bf16(al, bh1, acc[g1], 0, 0, 0);
        acc[g0] = __builtin_amdgcn_mfma_f32_32x32x16_bf16(ah, bl0, acc[g0], 0, 0, 0);
        acc[g1] = __builtin_amdgcn_mfma_f32_32x32x16_bf16(ah, bl1, acc[g1], 0, 0, 0);
      }
    }
#pragma unroll
    for (int reg = 0; reg < 16; ++reg) {
      int row32 = (reg & 3) + ((reg >> 2) << 3) + (hs << 2);
      float ig = fast_sigmoid(acc[0][reg]);
      float fg = fast_sigmoid(acc[1][reg]);
      float gg = fast_tanh  (acc[2][reg]);
      float og = fast_sigmoid(acc[3][reg]);
      float c  = fmaf(fg, c_reg[reg], ig * gg);
      c_reg[reg] = c;
      float h  = og * fast_tanh(c);
      unsigned short hi, lo;
      split_trunc(h, hi, lo);
      hfh[nbuf][coff + row32 * 8] = hi;
      hfl[nbuf][coff + row32 * 8] = lo;
      if (t == NHIST - 1) {
        hout[(b0 + row32) * HH + col] = h;
        cout[(b0 + row32) * HH + col] = c;
      }
    }
    __syncthreads();
    buf = nbuf;
  }
}

// -------------------------------- MC kernel --------------------------------
// 256 thr = 4 waves, 32 rows/block, 3 blocks/CU. Step t:
//   [wave1: z_t/logw]  kb loop (gates + am, all waves)  [t>0: x_t from am]
//   -> B1 -> epilogue (x-fold, h-write) -> B2.  No serial tail.
__launch_bounds__(256, 3)
__global__ void mc_kernel(const float* __restrict__ ret,
                          const float* __restrict__ W_ih,
                          const float* __restrict__ bias,
                          const unsigned short* __restrict__ Bhi,
                          const unsigned short* __restrict__ Blo,
                          const unsigned short* __restrict__ Bmu,
                          const float* __restrict__ hin,
                          const float* __restrict__ cin,
                          const float* __restrict__ b_mu,
                          const float* __restrict__ b_ls,
                          const uint32_t* __restrict__ keys,
                          float* __restrict__ accum) {
  __shared__ unsigned short hfh[2][HFN];
  __shared__ unsigned short hfl[HFN];
  __shared__ float x_s[32];
  __shared__ float mu_s[32];
  __shared__ float ls_s[32];
  __shared__ float z_s[2][32];   // parity-double-buffered z (wave 1 -> all)
  __shared__ float lw_s[32];     // final logw (wave 1 -> atomics)

  const int tid  = threadIdx.x;
  const int lane = tid & 63;
  const int cg   = tid >> 6;
  const int hs   = lane >> 5;
  const int m    = lane & 31;
  const int col  = (cg << 5) + m;

  const int s  = blockIdx.x >> 8;
  const int b0 = (blockIdx.x & 255) << 5;

  float wih_r[4], bb_r[4];
#pragma unroll
  for (int gi = 0; gi < 4; ++gi) {
    wih_r[gi] = W_ih[(gi << 7) + col];
    bb_r[gi]  = bias[(gi << 7) + col];
  }
  const float bmu = b_mu[0], bls = b_ls[0];

  const int coff = (col >> 4) * SKB + ((col >> 3) & 1) * SHS + (col & 7);
  const int aoff = hs * SHS + m * 8;

  // init h frags + c regs
  float c_reg[16];
#pragma unroll
  for (int reg = 0; reg < 16; ++reg) {
    int row32 = (reg & 3) + ((reg >> 2) << 3) + (hs << 2);
    int grow = b0 + row32;
    float hv = hin[grow * HH + col];
    c_reg[reg] = cin[grow * HH + col];
    unsigned short hi, lo;
    split_trunc(hv, hi, lo);
    hfh[0][coff + row32 * 8] = hi;
    hfl[coff + row32 * 8] = lo;
  }
  if (tid < 32) x_s[tid] = ret[126 * NB + b0 + tid];
  float logw = 0.0f, outv = 0.0f;
  __syncthreads();

  int buf = 0;
#pragma unroll 1
  for (int t = 0; t < NSTEP; ++t) {
    const int nbuf = buf ^ 1;

    // ---- wave 1: z_t + logw (state-independent; overlaps matmul)
    if (cg == 1) {
      uint32_t k0 = keys[2 * (s * NSTEP + t)];
      uint32_t k1 = keys[2 * (s * NSTEP + t) + 1];
      float z = normal32(k0, k1, (uint32_t)(b0 + m));
      logw -= fmaf(0.5f, z, 0.125f);   // lanes 32-63 duplicate lanes 0-31
      if (lane < 32) {
        z_s[t & 1][m] = z;             // consumed at step t+1 pre-B1
        if (t == NSTEP - 1) lw_s[m] = logw;
      }
    }

    // ---- gate + mu matmul from h_t (hfh[buf], hfl); all waves
    facc acc[4];
#pragma unroll
    for (int gi = 0; gi < 4; ++gi)
#pragma unroll
      for (int e = 0; e < 16; ++e) acc[gi][e] = 0.0f;
    facc am;
#pragma unroll
    for (int e = 0; e < 16; ++e) am[e] = 0.0f;
#pragma unroll 1
    for (int kb = 0; kb < 8; ++kb) {
      bfrag ah = *(const bfrag*)&hfh[buf][kb * SKB + aoff];
      bfrag al = *(const bfrag*)&hfl[kb * SKB + aoff];
      const bfrag bm = *(const bfrag*)&Bmu[kb * 512 + lane * 8];
#pragma unroll
      for (int gp = 0; gp < 2; ++gp) {
        const int g0 = 2 * gp, g1 = 2 * gp + 1;
        const int off0 = ((((g0 << 2) + cg) << 3) + kb) * 512 + lane * 8;
        const int off1 = ((((g1 << 2) + cg) << 3) + kb) * 512 + lane * 8;
        bfrag bh0 = *(const bfrag*)&Bhi[off0];
        bfrag bl0 = *(const bfrag*)&Blo[off0];
        bfrag bh1 = *(const bfrag*)&Bhi[off1];
        bfrag bl1 = *(const bfrag*)&Blo[off1];
        acc[g0] = __builtin_amdgcn_mfma_f32_32x32x16_bf16(ah, bh0, acc[g0], 0, 0, 0);
        acc[g1] = __builtin_amdgcn_mfma_f32_32x32x16_bf16(ah, bh1, acc[g1], 0, 0, 0);
        acc[g0] = __builtin_amdgcn_mfma_f32_32x32x16_bf16(al, bh0, acc[g0], 0, 0, 0);
        acc[g1] = __builtin_amdgcn_mfma_f32_32x32x16_bf16(al, bh1, acc[g1], 0, 0, 0);
        acc[g0] = __builtin_amdgcn_mfma_f32_32x32x16_bf16(ah, bl0, acc[g0], 0, 0, 0);
        acc[g1] = __builtin_amdgcn_mfma_f32_32x32x16_bf16(ah, bl1, acc[g1], 0, 0, 0);
      }
      am = __builtin_amdgcn_mfma_f32_32x32x16_bf16(ah, bm, am, 0, 0, 0);
    }

    // ---- pre-B1: x_t from am (t>=1), redundant on all waves (same values)
    if (t > 0) {
      if (m < 2) {
        float* dst = (m == 0) ? mu_s : ls_s;
#pragma unroll
        for (int reg = 0; reg < 16; ++reg)
          dst[(reg & 3) + ((reg >> 2) << 3) + (hs << 2)] = am[reg];
      }
      // same-wave LDS RAW: compiler inserts lgkmcnt wait; cross-wave writes
      // are identical values (benign)
      float mu  = mu_s[m] + bmu;
      float lsc = fminf(fmaxf(ls_s[m] + bls, -5.0f), 2.0f);
      float sg  = __expf(lsc);
      float z   = z_s[(t & 1) ^ 1][m];   // z_{t-1}, written at step t-1
      float xn  = fmaf(sg, z + 0.5f, mu);
      if (t == NSTEP - 1) outv = xn;     // x_19 = xs[TCAP]
      if (lane < 32) x_s[m] = xn;        // redundant same-value writes
    }
    __syncthreads();   // B1: reads done; x_s(t) visible

    // ---- epilogue: fold x*W_ih+b, activations, write hfh[nbuf] + hfl
#pragma unroll
    for (int reg = 0; reg < 16; ++reg) {
      int row32 = (reg & 3) + ((reg >> 2) << 3) + (hs << 2);
      float xv = x_s[row32];
      float ig = fast_sigmoid(acc[0][reg] + fmaf(xv, wih_r[0], bb_r[0]));
      float fg = fast_sigmoid(acc[1][reg] + fmaf(xv, wih_r[1], bb_r[1]));
      float gg = fast_tanh  (acc[2][reg] + fmaf(xv, wih_r[2], bb_r[2]));
      float og = fast_sigmoid(acc[3][reg] + fmaf(xv, wih_r[3], bb_r[3]));
      float c  = fmaf(fg, c_reg[reg], ig * gg);
      c_reg[reg] = c;
      float h  = og * fast_tanh(c);
      unsigned short hi, lo;
      split_trunc(h, hi, lo);
      hfh[nbuf][coff + row32 * 8] = hi;
      hfl[coff + row32 * 8] = lo;
    }
    __syncthreads();   // B2: h(t+1) frags visible for next kb loop
    buf = nbuf;
  }

  if (tid < 32) {
    float wt = __expf(lw_s[tid]);      // written by wave 1 at t=19
    float ow = outv * wt;
    int b = b0 + tid;
    atomicAdd(&accum[0 * NB + b], wt);
    atomicAdd(&accum[1 * NB + b], ow);
    atomicAdd(&accum[2 * NB + b], wt * wt);
    atomicAdd(&accum[3 * NB + b], ow * ow);
    atomicAdd(&accum[4 * NB + b], outv * wt * wt);
  }
}

// ------------------------------- final kernel ------------------------------
__global__ void final_kernel(const float* __restrict__ accum,
                             float* __restrict__ out) {
  int b = blockIdx.x * blockDim.x + threadIdx.x;
  if (b >= NB) return;
  float sw  = accum[0 * NB + b];
  float sm1 = accum[1 * NB + b];
  float sqw = accum[2 * NB + b];
  float sm2 = accum[3 * NB + b];
  float shm = accum[4 * NB + b];
  float mean = sm1 / sw;
  float sem = sm2 + sqw * mean * mean - 2.0f * shm * mean;
  sem = sqrtf(sem / (float)(NSAMP * (NSAMP - 1)));
  out[b] = mean;
  out[NB + b] = sem;
}

// ------------------------------- launcher ----------------------------------
extern "C" void kernel_launch(void* const* d_in, const int* in_sizes, int n_in,
                              void* d_out, int out_size, void* d_ws, size_t ws_size,
                              hipStream_t stream) {
  (void)in_sizes; (void)n_in; (void)out_size; (void)ws_size;
  const float* inp  = (const float*)d_in[0];
  const float* pert = (const float*)d_in[1];
  const float* W_ih = (const float*)d_in[2];
  const float* W_hh = (const float*)d_in[3];
  const float* bias = (const float*)d_in[4];
  const float* w_mu = (const float*)d_in[5];
  const float* b_mu = (const float*)d_in[6];
  const float* w_ls = (const float*)d_in[7];
  const float* b_ls = (const float*)d_in[8];

  char* ws = (char*)d_ws;
  float* ret = (float*)ws;        ws += (size_t)NRET * NB * sizeof(float);
  float* hh  = (float*)ws;        ws += (size_t)NB * HH * sizeof(float);
  float* cc  = (float*)ws;        ws += (size_t)NB * HH * sizeof(float);
  uint32_t* keys = (uint32_t*)ws; ws += (size_t)NSAMP * NSTEP * 2 * sizeof(uint32_t);
  float* accum = (float*)ws;      ws += (size_t)5 * NB * sizeof(float);
  unsigned short* Bhi = (unsigned short*)ws; ws += 65536 * sizeof(unsigned short);
  unsigned short* Blo = (unsigned short*)ws; ws += 65536 * sizeof(unsigned short);
  unsigned short* Bmu = (unsigned short*)ws; ws += 4096 * sizeof(unsigned short);

  hipMemsetAsync(accum, 0, (size_t)5 * NB * sizeof(float), stream);
  returns_kernel<<<(NRET * NB + 255) / 256, 256, 0, stream>>>(inp, pert, ret);
  keys_kernel<<<(NSAMP * NSTEP + 255) / 256, 256, 0, stream>>>(keys);
  pack_kernel<<<(65536 + 4096) / 256, 256, 0, stream>>>(W_hh, w_mu, w_ls, Bhi, Blo, Bmu);
  hist_kernel<<<NB / 32, 256, 0, stream>>>(ret, W_ih, bias, Bhi, Blo, hh, cc);
  mc_kernel<<<NSAMP * (NB / 32), 256, 0, stream>>>(ret, W_ih, bias, Bhi, Blo, Bmu,
      hh, cc, b_mu, b_ls, keys, accum);
  final_kernel<<<NB / 256, 256, 0, stream>>>(accum, (float*)d_out);
}

// Round 17
// 9396.621 us; speedup vs baseline: 1.1545x; 1.1545x over previous
//
#include <hip/hip_runtime.h>
#include <stdint.h>
#include <math.h>

// ---------------------------------------------------------------------------
// Round 17: REVERT to R13 (session best: 9.61 ms). R14 (4-wave diet), R15
// (z on wave 1), R16 (mu folded into kb loop) all regressed — the post-B2
// tail redistribution costs more than the tail (extra MFMA, Bmu fetch x4,
// LDS same-address write serialization: conflicts 1.6e7 -> 6.2e7). R13's
// config: 3 blocks/CU (148 unified regs/wave), 256thr/32-row blocks, hfh
// dbuf + hfl single, 2 barriers/step, wave-0 mu/RNG tail. ~75% combined
// pipe utilization; remaining stall is structural to the recurrent
// dependency (h_{t+1} needs full h_t matmul).
// ---------------------------------------------------------------------------

#define HH     128
#define NG     512
#define NB     8192
#define NSAMP  100
#define NSTEP  20
#define TCAP   18
#define NHIST  126
#define NRET   127

using bfrag = __attribute__((ext_vector_type(8))) short;   // 8 bf16 = 4 VGPRs
using facc  = __attribute__((ext_vector_type(16))) float;  // 16 f32 acc

// LDS frag strides (shorts): per-(kb,hs) region 264 (8 pad), per-kb 528.
#define SHS 264
#define SKB 528
#define HFN 4224   // 8 kb * 528

// ----------------------------- threefry2x32 --------------------------------
__device__ __forceinline__ void tf2x32(uint32_t k0, uint32_t k1,
                                       uint32_t x0, uint32_t x1,
                                       uint32_t &y0, uint32_t &y1) {
  uint32_t ks2 = k0 ^ k1 ^ 0x1BD11BDAu;
  x0 += k0; x1 += k1;
#define RR(r) { x0 += x1; x1 = (x1 << (r)) | (x1 >> (32 - (r))); x1 ^= x0; }
  RR(13) RR(15) RR(26) RR(6)   x0 += k1;  x1 += ks2 + 1u;
  RR(17) RR(29) RR(16) RR(24)  x0 += ks2; x1 += k0  + 2u;
  RR(13) RR(15) RR(26) RR(6)   x0 += k0;  x1 += k1  + 3u;
  RR(17) RR(29) RR(16) RR(24)  x0 += k1;  x1 += ks2 + 4u;
  RR(13) RR(15) RR(26) RR(6)   x0 += ks2; x1 += k0  + 5u;
#undef RR
  y0 = x0; y1 = x1;
}

__device__ __forceinline__ float erfinv32(float x) {
  float w = -__logf(fmaxf(1.0f - x * x, 1e-37f));
  float p;
  if (w < 5.0f) {
    w = w - 2.5f;
    p = 2.81022636e-08f;
    p = fmaf(p, w, 3.43273939e-07f);
    p = fmaf(p, w, -3.5233877e-06f);
    p = fmaf(p, w, -4.39150654e-06f);
    p = fmaf(p, w, 0.00021858087f);
    p = fmaf(p, w, -0.00125372503f);
    p = fmaf(p, w, -0.00417768164f);
    p = fmaf(p, w, 0.246640727f);
    p = fmaf(p, w, 1.50140941f);
  } else {
    w = sqrtf(w) - 3.0f;
    p = -0.000200214257f;
    p = fmaf(p, w, 0.000100950558f);
    p = fmaf(p, w, 0.00134934322f);
    p = fmaf(p, w, -0.00367342844f);
    p = fmaf(p, w, 0.00573950773f);
    p = fmaf(p, w, -0.0076224613f);
    p = fmaf(p, w, 0.00943887047f);
    p = fmaf(p, w, 1.00167406f);
    p = fmaf(p, w, 2.83297682f);
  }
  return p * x;
}

__device__ __forceinline__ float normal32(uint32_t k0, uint32_t k1, uint32_t idx) {
  uint32_t y0, y1;
  tf2x32(k0, k1, 0u, idx, y0, y1);
  uint32_t bits = y0 ^ y1;
  float f = __uint_as_float((bits >> 9) | 0x3f800000u) - 1.0f;
  const float lo = __uint_as_float(0xBF7FFFFFu);
  float u = fmaxf(lo, f * 2.0f + lo);
  return 1.41421356f * erfinv32(u);
}

__device__ __forceinline__ float fast_sigmoid(float x) {
  return __builtin_amdgcn_rcpf(1.0f + __expf(-x));
}
__device__ __forceinline__ float fast_tanh(float x) {
  return 1.0f - 2.0f * __builtin_amdgcn_rcpf(1.0f + __expf(2.0f * x));
}

// RNE bf16 (one-time B pack only)
__device__ __forceinline__ unsigned short f2bf(float x) {
  uint32_t u = __float_as_uint(x);
  uint32_t r = u + 0x7fffu + ((u >> 16) & 1u);
  return (unsigned short)(r >> 16);
}
__device__ __forceinline__ float bf2f(unsigned short h) {
  return __uint_as_float(((uint32_t)h) << 16);
}

// truncation split: hi = top16(h); lo = top16(h - hi) (Sterbenz-exact sub)
__device__ __forceinline__ void split_trunc(float h, unsigned short &hi,
                                            unsigned short &lo) {
  uint32_t u = __float_as_uint(h);
  hi = (unsigned short)(u >> 16);
  float hv = __uint_as_float(u & 0xFFFF0000u);
  lo = (unsigned short)(__float_as_uint(h - hv) >> 16);
}

// ------------------------------- small kernels -----------------------------
__global__ void returns_kernel(const float* __restrict__ inp,
                               const float* __restrict__ pert,
                               float* __restrict__ ret) {
  int i = blockIdx.x * blockDim.x + threadIdx.x;
  if (i >= NRET * NB) return;
  int s = i / NB, b = i - s * NB;
  float p0 = inp[s * NB + b] * (1.0f + pert[s * NB + b]);
  float p1 = inp[(s + 1) * NB + b] * (1.0f + pert[(s + 1) * NB + b]);
  ret[i] = p1 - p0;
}

__global__ void keys_kernel(uint32_t* __restrict__ keys) {
  int id = blockIdx.x * blockDim.x + threadIdx.x;
  if (id >= NSAMP * NSTEP) return;
  int s = id / NSTEP, t = id - s * NSTEP;
  uint32_t sk0, sk1, k0, k1;
  tf2x32(0u, 42u, 0u, (uint32_t)s, sk0, sk1);
  tf2x32(sk0, sk1, 0u, (uint32_t)t, k0, k1);
  keys[2 * id] = k0; keys[2 * id + 1] = k1;
}

// B-fragment pack (RNE): Bhi/Blo[((gct*8+kb)*64+lane)*8+j]
__global__ void pack_kernel(const float* __restrict__ W_hh,
                            const float* __restrict__ w_mu,
                            const float* __restrict__ w_ls,
                            unsigned short* __restrict__ Bhi,
                            unsigned short* __restrict__ Blo,
                            unsigned short* __restrict__ Bmu) {
  int idx = blockIdx.x * blockDim.x + threadIdx.x;
  if (idx < 65536) {
    int j = idx & 7, lane = (idx >> 3) & 63, kb = (idx >> 9) & 7, gct = idx >> 12;
    int k = kb * 16 + ((lane >> 5) << 3) + j;
    int g = (gct << 5) + (lane & 31);
    float w = W_hh[k * NG + g];
    unsigned short hi = f2bf(w);
    unsigned short lo = f2bf(w - bf2f(hi));
    Bhi[idx] = hi; Blo[idx] = lo;
  } else if (idx < 65536 + 4096) {
    int i2 = idx - 65536;
    int j = i2 & 7, lane = (i2 >> 3) & 63, kb = (i2 >> 9) & 7;
    int k = kb * 16 + ((lane >> 5) << 3) + j;
    int col = lane & 31;
    float v = (col == 0) ? w_mu[k] : (col == 1 ? w_ls[k] : 0.0f);
    Bmu[i2] = f2bf(v);
  }
}

// ------------------------------ history kernel -----------------------------
__launch_bounds__(256, 1)
__global__ void hist_kernel(const float* __restrict__ ret,
                            const float* __restrict__ W_ih,
                            const float* __restrict__ bias,
                            const unsigned short* __restrict__ Bhi,
                            const unsigned short* __restrict__ Blo,
                            float* __restrict__ hout,
                            float* __restrict__ cout) {
  __shared__ unsigned short hfh[2][HFN];
  __shared__ unsigned short hfl[2][HFN];

  const int tid  = threadIdx.x;
  const int lane = tid & 63;
  const int cg   = tid >> 6;
  const int hs   = lane >> 5;
  const int m    = lane & 31;
  const int col  = (cg << 5) + m;
  const int b0   = blockIdx.x << 5;

  float wih_r[4], bb_r[4];
#pragma unroll
  for (int gi = 0; gi < 4; ++gi) {
    wih_r[gi] = W_ih[(gi << 7) + col];
    bb_r[gi]  = bias[(gi << 7) + col];
  }

  const int coff = (col >> 4) * SKB + ((col >> 3) & 1) * SHS + (col & 7);
  const int aoff = hs * SHS + m * 8;

  float c_reg[16];
#pragma unroll
  for (int reg = 0; reg < 16; ++reg) {
    int row32 = (reg & 3) + ((reg >> 2) << 3) + (hs << 2);
    c_reg[reg] = 0.0f;
    hfh[0][coff + row32 * 8] = 0;
    hfl[0][coff + row32 * 8] = 0;
  }
  __syncthreads();

  int buf = 0;
#pragma unroll 1
  for (int t = 0; t < NHIST; ++t) {
    const int nbuf = buf ^ 1;
    facc acc[4];
#pragma unroll
    for (int reg = 0; reg < 16; ++reg) {
      int row32 = (reg & 3) + ((reg >> 2) << 3) + (hs << 2);
      float xv = ret[t * NB + b0 + row32];
#pragma unroll
      for (int gi = 0; gi < 4; ++gi)
        acc[gi][reg] = fmaf(xv, wih_r[gi], bb_r[gi]);
    }
#pragma unroll 1
    for (int kb = 0; kb < 8; ++kb) {
      bfrag ah = *(const bfrag*)&hfh[buf][kb * SKB + aoff];
      bfrag al = *(const bfrag*)&hfl[buf][kb * SKB + aoff];
#pragma unroll
      for (int gp = 0; gp < 2; ++gp) {
        const int g0 = 2 * gp, g1 = 2 * gp + 1;
        const int off0 = ((((g0 << 2) + cg) << 3) + kb) * 512 + lane * 8;
        const int off1 = ((((g1 << 2) + cg) << 3) + kb) * 512 + lane * 8;
        bfrag bh0 = *(const bfrag*)&Bhi[off0];
        bfrag bl0 = *(const bfrag*)&Blo[off0];
        bfrag bh1 = *(const bfrag*)&Bhi[off1];
        bfrag bl1 = *(const bfrag*)&Blo[off1];
        acc[g0] = __builtin_amdgcn_mfma_f32_32x32x16_bf16(ah, bh0, acc[g0], 0, 0, 0);
        acc[g1] = __builtin_amdgcn_mfma_f32_32x32x16_bf16(ah, bh1, acc[g1], 0, 0, 0);
        acc[g0] = __builtin_amdgcn_mfma_f32_32x32x16_bf16(al, bh0, acc[g0], 0, 0, 0);
        acc[g1] = __builtin_amdgcn_mfma_f32_32x32x16_bf16(al, bh1, acc[g1], 0, 0, 0);
        acc[g0] = __builtin_amdgcn_mfma_f32_32x32x16_bf16(ah, bl0, acc[g0], 0, 0, 0);
        acc[g1] = __builtin_amdgcn_mfma_f32_32x32x16_bf16(ah, bl1, acc[g1], 0, 0, 0);
      }
    }
#pragma unroll
    for (int reg = 0; reg < 16; ++reg) {
      int row32 = (reg & 3) + ((reg >> 2) << 3) + (hs << 2);
      float ig = fast_sigmoid(acc[0][reg]);
      float fg = fast_sigmoid(acc[1][reg]);
      float gg = fast_tanh  (acc[2][reg]);
      float og = fast_sigmoid(acc[3][reg]);
      float c  = fmaf(fg, c_reg[reg], ig * gg);
      c_reg[reg] = c;
      float h  = og * fast_tanh(c);
      unsigned short hi, lo;
      split_trunc(h, hi, lo);
      hfh[nbuf][coff + row32 * 8] = hi;
      hfl[nbuf][coff + row32 * 8] = lo;
      if (t == NHIST - 1) {
        hout[(b0 + row32) * HH + col] = h;
        cout[(b0 + row32) * HH + col] = c;
      }
    }
    __syncthreads();
    buf = nbuf;
  }
}

// -------------------------------- MC kernel --------------------------------
__launch_bounds__(256, 3)
__global__ void mc_kernel(const float* __restrict__ ret,
                          const float* __restrict__ W_ih,
                          const float* __restrict__ bias,
                          const unsigned short* __restrict__ Bhi,
                          const unsigned short* __restrict__ Blo,
                          const unsigned short* __restrict__ Bmu,
                          const float* __restrict__ hin,
                          const float* __restrict__ cin,
                          const float* __restrict__ b_mu,
                          const float* __restrict__ b_ls,
                          const uint32_t* __restrict__ keys,
                          float* __restrict__ accum) {
  __shared__ unsigned short hfh[2][HFN];
  __shared__ unsigned short hfl[HFN];
  __shared__ float x_s[32];
  __shared__ float mu_s[32];
  __shared__ float ls_s[32];

  const int tid  = threadIdx.x;
  const int lane = tid & 63;
  const int cg   = tid >> 6;
  const int hs   = lane >> 5;
  const int m    = lane & 31;
  const int col  = (cg << 5) + m;

  const int s  = blockIdx.x >> 8;
  const int b0 = (blockIdx.x & 255) << 5;

  float wih_r[4], bb_r[4];
#pragma unroll
  for (int gi = 0; gi < 4; ++gi) {
    wih_r[gi] = W_ih[(gi << 7) + col];
    bb_r[gi]  = bias[(gi << 7) + col];
  }
  const float bmu = b_mu[0], bls = b_ls[0];

  const int coff = (col >> 4) * SKB + ((col >> 3) & 1) * SHS + (col & 7);
  const int aoff = hs * SHS + m * 8;

  // init h frags + c regs
  float c_reg[16];
#pragma unroll
  for (int reg = 0; reg < 16; ++reg) {
    int row32 = (reg & 3) + ((reg >> 2) << 3) + (hs << 2);
    int grow = b0 + row32;
    float hv = hin[grow * HH + col];
    c_reg[reg] = cin[grow * HH + col];
    unsigned short hi, lo;
    split_trunc(hv, hi, lo);
    hfh[0][coff + row32 * 8] = hi;
    hfl[coff + row32 * 8] = lo;
  }
  if (tid < 32) x_s[tid] = ret[126 * NB + b0 + tid];
  float logw = 0.0f, outv = 0.0f;
  __syncthreads();

  int buf = 0;
#pragma unroll 1
  for (int t = 0; t < NSTEP; ++t) {
    const int nbuf = buf ^ 1;

    // ---- gate matmul from h_t (hfh[buf], hfl); acc starts at 0
    facc acc[4];
#pragma unroll
    for (int gi = 0; gi < 4; ++gi)
#pragma unroll
      for (int e = 0; e < 16; ++e) acc[gi][e] = 0.0f;
#pragma unroll 1
    for (int kb = 0; kb < 8; ++kb) {
      bfrag ah = *(const bfrag*)&hfh[buf][kb * SKB + aoff];
      bfrag al = *(const bfrag*)&hfl[kb * SKB + aoff];
#pragma unroll
      for (int gp = 0; gp < 2; ++gp) {
        const int g0 = 2 * gp, g1 = 2 * gp + 1;
        const int off0 = ((((g0 << 2) + cg) << 3) + kb) * 512 + lane * 8;
        const int off1 = ((((g1 << 2) + cg) << 3) + kb) * 512 + lane * 8;
        bfrag bh0 = *(const bfrag*)&Bhi[off0];
        bfrag bl0 = *(const bfrag*)&Blo[off0];
        bfrag bh1 = *(const bfrag*)&Bhi[off1];
        bfrag bl1 = *(const bfrag*)&Blo[off1];
        acc[g0] = __builtin_amdgcn_mfma_f32_32x32x16_bf16(ah, bh0, acc[g0], 0, 0, 0);
        acc[g1] = __builtin_amdgcn_mfma_f32_32x32x16_bf16(ah, bh1, acc[g1], 0, 0, 0);
        acc[g0] = __builtin_amdgcn_mfma_f32_32x32x16_bf16(al, bh0, acc[g0], 0, 0, 0);
        acc[g1] = __builtin_amdgcn_mfma_f32_32x32x16_bf16(al, bh1, acc[g1], 0, 0, 0);
        acc[g0] = __builtin_amdgcn_mfma_f32_32x32x16_bf16(ah, bl0, acc[g0], 0, 0, 0);
        acc[g1] = __builtin_amdgcn_mfma_f32_32x32x16_bf16(ah, bl1, acc[g1], 0, 0, 0);
      }
    }
    __syncthreads();   // B1: all hfh[buf]/hfl reads done; x_s(t) visible

    // ---- epilogue: fold x*W_ih+b, activations, write hfh[nbuf] + hfl
#pragma unroll
    for (int reg = 0; reg < 16; ++reg) {
      int row32 = (reg & 3) + ((reg >> 2) << 3) + (hs << 2);
      float xv = x_s[row32];
      float ig = fast_sigmoid(acc[0][reg] + fmaf(xv, wih_r[0], bb_r[0]));
      float fg = fast_sigmoid(acc[1][reg] + fmaf(xv, wih_r[1], bb_r[1]));
      float gg = fast_tanh  (acc[2][reg] + fmaf(xv, wih_r[2], bb_r[2]));
      float og = fast_sigmoid(acc[3][reg] + fmaf(xv, wih_r[3], bb_r[3]));
      float c  = fmaf(fg, c_reg[reg], ig * gg);
      c_reg[reg] = c;
      float h  = og * fast_tanh(c);
      unsigned short hi, lo;
      split_trunc(h, hi, lo);
      hfh[nbuf][coff + row32 * 8] = hi;
      hfl[coff + row32 * 8] = lo;
    }
    __syncthreads();   // B2: h(t+1) frags visible

    if (tid < 64) {    // wave 0: mu/ls MFMA on hfh[nbuf] + RNG + x_s(t+1)
      facc am;
#pragma unroll
      for (int e = 0; e < 16; ++e) am[e] = 0.0f;
#pragma unroll 2
      for (int kb = 0; kb < 8; ++kb) {
        const bfrag bm = *(const bfrag*)&Bmu[kb * 512 + lane * 8];
        const bfrag a0 = *(const bfrag*)&hfh[nbuf][kb * SKB + aoff];
        am = __builtin_amdgcn_mfma_f32_32x32x16_bf16(a0, bm, am, 0, 0, 0);
      }
      if (m < 2) {
        float* dst = (m == 0) ? mu_s : ls_s;
#pragma unroll
        for (int reg = 0; reg < 16; ++reg)
          dst[(reg & 3) + ((reg >> 2) << 3) + (hs << 2)] = am[reg];
      }
      // same-wave LDS RAW: compiler inserts lgkmcnt wait
      float mu  = mu_s[m] + bmu;
      float lsc = fminf(fmaxf(ls_s[m] + bls, -5.0f), 2.0f);
      float sg  = __expf(lsc);
      uint32_t k0 = keys[2 * (s * NSTEP + t)];
      uint32_t k1 = keys[2 * (s * NSTEP + t) + 1];
      float z  = normal32(k0, k1, (uint32_t)(b0 + m));
      float xn = fmaf(sg, z + 0.5f, mu);
      logw -= fmaf(0.5f, z, 0.125f);
      if (t == TCAP) outv = xn;
      if (lane < 32) x_s[lane] = xn;   // visible to consumers via next B1
    }
    buf = nbuf;
  }

  if (tid < 32) {
    float wt = __expf(logw);
    float ow = outv * wt;
    int b = b0 + tid;
    atomicAdd(&accum[0 * NB + b], wt);
    atomicAdd(&accum[1 * NB + b], ow);
    atomicAdd(&accum[2 * NB + b], wt * wt);
    atomicAdd(&accum[3 * NB + b], ow * ow);
    atomicAdd(&accum[4 * NB + b], outv * wt * wt);
  }
}

// ------------------------------- final kernel ------------------------------
__global__ void final_kernel(const float* __restrict__ accum,
                             float* __restrict__ out) {
  int b = blockIdx.x * blockDim.x + threadIdx.x;
  if (b >= NB) return;
  float sw  = accum[0 * NB + b];
  float sm1 = accum[1 * NB + b];
  float sqw = accum[2 * NB + b];
  float sm2 = accum[3 * NB + b];
  float shm = accum[4 * NB + b];
  float mean = sm1 / sw;
  float sem = sm2 + sqw * mean * mean - 2.0f * shm * mean;
  sem = sqrtf(sem / (float)(NSAMP * (NSAMP - 1)));
  out[b] = mean;
  out[NB + b] = sem;
}

// ------------------------------- launcher ----------------------------------
extern "C" void kernel_launch(void* const* d_in, const int* in_sizes, int n_in,
                              void* d_out, int out_size, void* d_ws, size_t ws_size,
                              hipStream_t stream) {
  (void)in_sizes; (void)n_in; (void)out_size; (void)ws_size;
  const float* inp  = (const float*)d_in[0];
  const float* pert = (const float*)d_in[1];
  const float* W_ih = (const float*)d_in[2];
  const float* W_hh = (const float*)d_in[3];
  const float* bias = (const float*)d_in[4];
  const float* w_mu = (const float*)d_in[5];
  const float* b_mu = (const float*)d_in[6];
  const float* w_ls = (const float*)d_in[7];
  const float* b_ls = (const float*)d_in[8];

  char* ws = (char*)d_ws;
  float* ret = (float*)ws;        ws += (size_t)NRET * NB * sizeof(float);
  float* hh  = (float*)ws;        ws += (size_t)NB * HH * sizeof(float);
  float* cc  = (float*)ws;        ws += (size_t)NB * HH * sizeof(float);
  uint32_t* keys = (uint32_t*)ws; ws += (size_t)NSAMP * NSTEP * 2 * sizeof(uint32_t);
  float* accum = (float*)ws;      ws += (size_t)5 * NB * sizeof(float);
  unsigned short* Bhi = (unsigned short*)ws; ws += 65536 * sizeof(unsigned short);
  unsigned short* Blo = (unsigned short*)ws; ws += 65536 * sizeof(unsigned short);
  unsigned short* Bmu = (unsigned short*)ws; ws += 4096 * sizeof(unsigned short);

  hipMemsetAsync(accum, 0, (size_t)5 * NB * sizeof(float), stream);
  returns_kernel<<<(NRET * NB + 255) / 256, 256, 0, stream>>>(inp, pert, ret);
  keys_kernel<<<(NSAMP * NSTEP + 255) / 256, 256, 0, stream>>>(keys);
  pack_kernel<<<(65536 + 4096) / 256, 256, 0, stream>>>(W_hh, w_mu, w_ls, Bhi, Blo, Bmu);
  hist_kernel<<<NB / 32, 256, 0, stream>>>(ret, W_ih, bias, Bhi, Blo, hh, cc);
  mc_kernel<<<NSAMP * (NB / 32), 256, 0, stream>>>(ret, W_ih, bias, Bhi, Blo, Bmu,
      hh, cc, b_mu, b_ls, keys, accum);
  final_kernel<<<NB / 256, 256, 0, stream>>>(accum, (float*)d_out);
}